// Round 11
// baseline (2466.078 us; speedup 1.0000x reference)
//
#include <hip/hip_runtime.h>
#include <hip/hip_bf16.h>
#include <math.h>

#define B_ 32
#define S_ 100
#define D_ 1024
#define H_ 16
#define L_ 2
#define V_ 32000
#define DF_ 4096
#define HD_ 64
#define MPAD 3328   // 3200 padded to 13*256
#define NPART 2048  // absmean partial count

typedef __bf16 bf16x8 __attribute__((ext_vector_type(8)));
typedef float f32x4 __attribute__((ext_vector_type(4)));

__device__ __forceinline__ void async_copy16(const void* g, void* l) {
  __builtin_amdgcn_global_load_lds((const __attribute__((address_space(1))) void*)g,
                                   (__attribute__((address_space(3))) void*)l, 16, 0, 0);
}

// ------------------------------------------------------------------
// per-block |w| partial sums in f64 (no atomics, no memset; every
// entry rewritten each launch -> no cross-replay state)
// ------------------------------------------------------------------
__global__ __launch_bounds__(256) void absmean_kernel(const float* __restrict__ w,
                                                      double* __restrict__ part) {
  const long long n4 = (long long)V_ * D_ / 4;
  double s = 0.0;
  long long stride = (long long)gridDim.x * blockDim.x;
  for (long long i = (long long)blockIdx.x * blockDim.x + threadIdx.x; i < n4; i += stride) {
    float4 v = ((const float4*)w)[i];
    s += (double)fabsf(v.x) + (double)fabsf(v.y) + (double)fabsf(v.z) + (double)fabsf(v.w);
  }
#pragma unroll
  for (int off = 32; off > 0; off >>= 1) s += __shfl_down(s, off);
  __shared__ double sm[4];
  int lane = threadIdx.x & 63, wv = threadIdx.x >> 6;
  if (lane == 0) sm[wv] = s;
  __syncthreads();
  if (threadIdx.x == 0) part[blockIdx.x] = sm[0] + sm[1] + sm[2] + sm[3];
}

// packed effective ternary weight as bf16: {q==0:+1, q==+1:-1, q==-1:0}
// Each block first reduces the 2048 partials in a FIXED order (bitwise
// deterministic, identical across blocks), then quantizes with w*inv_g
// (<=1ulp vs w/g, below the ~1e-13 reduction-order band already accepted).
__global__ __launch_bounds__(256) void quantize_kernel(const float* __restrict__ w,
    const double* __restrict__ part, __hip_bfloat16* __restrict__ q) {
  __shared__ double gsh;
  {
    double p = 0.0;
    for (int i = threadIdx.x; i < NPART; i += 256) p += part[i];
#pragma unroll
    for (int off = 32; off > 0; off >>= 1) p += __shfl_down(p, off);
    __shared__ double sm[4];
    int lane = threadIdx.x & 63, wv = threadIdx.x >> 6;
    if (lane == 0) sm[wv] = p;
    __syncthreads();
    if (threadIdx.x == 0) gsh = sm[0] + sm[1] + sm[2] + sm[3];
    __syncthreads();
  }
  double g = gsh / ((double)V_ * D_) + 1e-6;
  double inv_g = 1.0 / g;
  const long long n4 = (long long)V_ * D_ / 4;
  long long stride = (long long)gridDim.x * blockDim.x;
  for (long long i = (long long)blockIdx.x * blockDim.x + threadIdx.x; i < n4; i += stride) {
    float4 v = ((const float4*)w)[i];
    union { __hip_bfloat16 h[4]; uint2 u; } o;
    float vv[4] = {v.x, v.y, v.z, v.w};
#pragma unroll
    for (int j = 0; j < 4; ++j) {
      double r = rint((double)vv[j] * inv_g);  // half-to-even, matches np.round
      r = fmin(1.0, fmax(-1.0, r));
      float w_eff = (r == 0.0) ? 1.0f : ((r == 1.0) ? -1.0f : 0.0f);
      o.h[j] = __float2bfloat16(w_eff);  // exact
    }
    ((uint2*)q)[i] = o.u;
  }
}

// ------------------------------------------------------------------
// fused: blocks [0,3200) embed one row each (h fp32 + h_bf bf16);
// blocks [3200, 3200+4096) grid-stride cast the four weight tensors.
// ------------------------------------------------------------------
__global__ __launch_bounds__(256) void prep_kernel(const int* __restrict__ x,
    const float* __restrict__ emb, const float* __restrict__ pos,
    float* __restrict__ h, __hip_bfloat16* __restrict__ hb,
    const float* __restrict__ qkv_w, const float* __restrict__ out_w,
    const float* __restrict__ ff1_w, const float* __restrict__ ff2_w,
    __hip_bfloat16* __restrict__ qd, __hip_bfloat16* __restrict__ od,
    __hip_bfloat16* __restrict__ f1d, __hip_bfloat16* __restrict__ f2d) {
  if (blockIdx.x < 3200) {
    int row = blockIdx.x;  // b*S + s
    int s = row % S_;
    int tok = x[row];
    size_t eb = (size_t)tok * D_, pb = (size_t)s * D_, hb0 = (size_t)row * D_;
#pragma unroll
    for (int i = 0; i < 4; ++i) {
      int d = threadIdx.x + i * 256;
      float v = emb[eb + d] + pos[pb + d];
      h[hb0 + d] = v;
      hb[hb0 + d] = __float2bfloat16(v);
    }
    return;
  }
  const long long n1 = (long long)2 * 3072 * 1024 / 4;
  const long long n2 = n1 + (long long)2 * 1024 * 1024 / 4;
  const long long n3 = n2 + (long long)2 * 4096 * 1024 / 4;
  const long long n4 = n3 + (long long)2 * 1024 * 4096 / 4;
  long long cb = (long long)(blockIdx.x - 3200);
  long long stride = (long long)(gridDim.x - 3200) * blockDim.x;
  for (long long i = cb * blockDim.x + threadIdx.x; i < n4; i += stride) {
    const float* src; __hip_bfloat16* dst; long long j;
    if (i < n1)      { src = qkv_w; dst = qd;  j = i; }
    else if (i < n2) { src = out_w; dst = od;  j = i - n1; }
    else if (i < n3) { src = ff1_w; dst = f1d; j = i - n2; }
    else             { src = ff2_w; dst = f2d; j = i - n3; }
    float4 v = ((const float4*)src)[j];
    union { __hip_bfloat16 h[4]; uint2 u; } o;
    o.h[0] = __float2bfloat16(v.x);
    o.h[1] = __float2bfloat16(v.y);
    o.h[2] = __float2bfloat16(v.z);
    o.h[3] = __float2bfloat16(v.w);
    ((uint2*)dst)[j] = o.u;
  }
}

__device__ __forceinline__ float gelu_exact(float v) {
  return 0.5f * v * (1.0f + erff(v * 0.70710678118654752f));
}

// ------------------------------------------------------------------
// m97-structure bf16 MFMA GEMM, 128x128 tile, BK=64 single-buffered
// (R6-proven; explicit dbuf regressed by cutting occupancy). Split-K
// via blockIdx.z (z=0 -> C+bias, z=1 -> C2). XCD-bijective swizzle.
// ------------------------------------------------------------------
template <int ACT, int OUTBF>
__global__ __launch_bounds__(256) void gemm_bf(const __hip_bfloat16* __restrict__ A,
    const __hip_bfloat16* __restrict__ Bm, const float* __restrict__ bias,
    void* __restrict__ C, void* __restrict__ C2, int M, int N, int K, int lda, int ldb) {
  __shared__ __bf16 As[128 * 64];  // [0..8191B] k0-31, [8192..16383B] k32-63
  __shared__ __bf16 Bs[128 * 64];
  int tid = threadIdx.x;
  int lane = tid & 63, wid = tid >> 6;
  int wr = wid >> 1, wc = wid & 1;  // wave -> 64x64 quadrant
  int z = blockIdx.z;

  // ---- bijective XCD swizzle (T1 / m204) ----
  int nwg = gridDim.x * gridDim.y;
  int orig = blockIdx.y * gridDim.x + blockIdx.x;
  int q = nwg >> 3, r = nwg & 7;
  int xcd = orig & 7, local = orig >> 3;
  int wgid = (xcd < r ? xcd * (q + 1) : r * (q + 1) + (xcd - r) * q) + local;
  int row0 = (wgid % gridDim.x) * 128;  // gridDim.x = M/128 (M fastest)
  int col0 = (wgid / gridDim.x) * 128;

  const __hip_bfloat16* Az = A + (size_t)z * K;
  const __hip_bfloat16* Bz = Bm + (size_t)z * K;
  int j0 = wid * 2;
  const __hip_bfloat16* Ag0 = Az + (size_t)(row0 + j0 * 16 + (lane >> 2)) * lda + (lane & 3) * 8;
  const __hip_bfloat16* Ag1 = Az + (size_t)(row0 + (j0 + 1) * 16 + (lane >> 2)) * lda + (lane & 3) * 8;
  const __hip_bfloat16* Bg0 = Bz + (size_t)(col0 + j0 * 16 + (lane >> 2)) * ldb + (lane & 3) * 8;
  const __hip_bfloat16* Bg1 = Bz + (size_t)(col0 + (j0 + 1) * 16 + (lane >> 2)) * ldb + (lane & 3) * 8;
  __bf16* Al0 = As + j0 * 512;
  __bf16* Al1 = As + (j0 + 1) * 512;
  __bf16* Bl0 = Bs + j0 * 512;
  __bf16* Bl1 = Bs + (j0 + 1) * 512;

  float bias_v[4];
#pragma unroll
  for (int ni = 0; ni < 4; ++ni)
    bias_v[ni] = (z == 0) ? bias[col0 + wc * 64 + ni * 16 + (lane & 15)] : 0.f;

  f32x4 acc[4][4];
#pragma unroll
  for (int mi = 0; mi < 4; ++mi)
#pragma unroll
    for (int ni = 0; ni < 4; ++ni) acc[mi][ni] = (f32x4){0.f, 0.f, 0.f, 0.f};

  const bf16x8* Asv = reinterpret_cast<const bf16x8*>(As);
  const bf16x8* Bsv = reinterpret_cast<const bf16x8*>(Bs);
  int afr = (wr * 64 + (lane & 15)) * 4 + (lane >> 4);  // in 8-elem units
  int bfr = (wc * 64 + (lane & 15)) * 4 + (lane >> 4);

  for (int k0 = 0; k0 < K; k0 += 64) {
    async_copy16(Ag0, Al0);  async_copy16(Ag0 + 32, (char*)Al0 + 8192);
    async_copy16(Ag1, Al1);  async_copy16(Ag1 + 32, (char*)Al1 + 8192);
    async_copy16(Bg0, Bl0);  async_copy16(Bg0 + 32, (char*)Bl0 + 8192);
    async_copy16(Bg1, Bl1);  async_copy16(Bg1 + 32, (char*)Bl1 + 8192);
    Ag0 += 64; Ag1 += 64; Bg0 += 64; Bg1 += 64;
    __syncthreads();  // drains vmcnt: LDS tile visible to all waves
    bf16x8 af[4][2], bq[4][2];
#pragma unroll
    for (int mi = 0; mi < 4; ++mi)
#pragma unroll
      for (int kk = 0; kk < 2; ++kk) af[mi][kk] = Asv[afr + mi * 64 + kk * 512];
#pragma unroll
    for (int ni = 0; ni < 4; ++ni)
#pragma unroll
      for (int kk = 0; kk < 2; ++kk) bq[ni][kk] = Bsv[bfr + ni * 64 + kk * 512];
#pragma unroll
    for (int mi = 0; mi < 4; ++mi)
#pragma unroll
      for (int ni = 0; ni < 4; ++ni)
#pragma unroll
        for (int kk = 0; kk < 2; ++kk)
          acc[mi][ni] = __builtin_amdgcn_mfma_f32_16x16x32_bf16(af[mi][kk], bq[ni][kk], acc[mi][ni], 0, 0, 0);
    __syncthreads();  // compute done before next-tile overwrite
  }

  float* Cf = (float*)((z == 0) ? C : C2);
  __hip_bfloat16* Cb = (__hip_bfloat16*)C;
#pragma unroll
  for (int mi = 0; mi < 4; ++mi) {
#pragma unroll
    for (int r2 = 0; r2 < 4; ++r2) {
      size_t m = row0 + wr * 64 + mi * 16 + (lane >> 4) * 4 + r2;
#pragma unroll
      for (int ni = 0; ni < 4; ++ni) {
        size_t n = col0 + wc * 64 + ni * 16 + (lane & 15);
        float v = acc[mi][ni][r2] + bias_v[ni];
        if (ACT == 1) v = gelu_exact(v);
        if (OUTBF) Cb[m * N + n] = __float2bfloat16(v);
        else       Cf[m * N + n] = v;
      }
    }
  }
}

// ------------------------------------------------------------------
// 8-phase 256x256 GEMM (T2+T3+T4+T5), BK template {64,32}, 512 threads
// = 8 waves (2M x 4N), per-wave 128x64 output. Raw s_barrier + counted
// vmcnt; XOR swizzle via pre-swizzled global source. BK=64: LDS 128KB,
// 1 block/CU (single-cohort grids). BK=32: LDS 64KB -> 2 blocks/CU
// (cross-block overlap hides barrier drain; for the 1625-block decoder).
// Row stride is 64B in both cases, so all lane/mi/wn offsets identical;
// vmcnt = loads of last 2 stages in flight (BK=64: 4, BK=32: 2).
// ------------------------------------------------------------------
template <int ACT, int OUTBF, int BK>
__global__ __launch_bounds__(512, BK == 32 ? 4 : 1) void gemm256(
    const __hip_bfloat16* __restrict__ A, const __hip_bfloat16* __restrict__ Bm,
    const float* __restrict__ bias, void* __restrict__ C,
    int Mreal, int N, int K) {
  constexpr int HALF = 128 * BK * 2;   // bytes per (128-row x BK-col) half
  constexpr int BUF = 2 * HALF;        // bytes per dbuf slot (2 halves)
  constexpr int NKK = BK / 32;
  extern __shared__ char lds[];
  char* ldsA = lds;                    // 2*BUF
  char* ldsB = lds + 2 * BUF;
  const int t = threadIdx.x;
  const int lane = t & 63, wid = t >> 6;
  const int wm = wid >> 2, wn = wid & 3;
  const int NT = K / BK;

  // bijective XCD swizzle, M fastest
  int nwg = gridDim.x * gridDim.y;
  int orig = blockIdx.y * gridDim.x + blockIdx.x;
  int q = nwg >> 3, r = nwg & 7;
  int xcd = orig & 7, local = orig >> 3;
  int wgid = (xcd < r ? xcd * (q + 1) : r * (q + 1) + (xcd - r) * q) + local;
  int row0 = (wgid % gridDim.x) * 256;
  int col0 = (wgid / gridDim.x) * 256;

  const int rs = t >> 2;                                           // 0..127
  const int kc = ((((t & 3) << 4) ^ (((t >> 5) & 1) << 5)) >> 1);  // 0..31 elems
  const __hip_bfloat16* Asrc = A + (size_t)(row0 + rs) * K + kc;
  const __hip_bfloat16* Bsrc = Bm + (size_t)(col0 + rs) * K + kc;

#define STAGE_A(b, h, tgt) do { \
    const __hip_bfloat16* _s = Asrc + (size_t)(h) * 128 * K + (tgt) * BK; \
    char* _d = ldsA + (b) * BUF + (h) * HALF + t * 16; \
    async_copy16(_s, _d); \
    if constexpr (BK == 64) async_copy16(_s + 32, _d + 8192); } while (0)
#define STAGE_B(b, h, tgt) do { \
    const __hip_bfloat16* _s = Bsrc + (size_t)(h) * 128 * K + (tgt) * BK; \
    char* _d = ldsB + (b) * BUF + (h) * HALF + t * 16; \
    async_copy16(_s, _d); \
    if constexpr (BK == 64) async_copy16(_s + 32, _d + 8192); } while (0)
#define SB() __builtin_amdgcn_sched_barrier(0)
#define BAR() __builtin_amdgcn_s_barrier()
#define VMC_STEADY() do { \
    if constexpr (BK == 64) asm volatile("s_waitcnt vmcnt(4)" ::: "memory"); \
    else                    asm volatile("s_waitcnt vmcnt(2)" ::: "memory"); } while (0)

  const int sb5 = ((lane >> 3) & 1) << 5;
  const int laneoff = ((lane & 15) << 6) + (((lane >> 4) << 4) ^ sb5);

  f32x4 acc[8][4];
#pragma unroll
  for (int i = 0; i < 8; ++i)
#pragma unroll
    for (int j = 0; j < 4; ++j) acc[i][j] = (f32x4){0.f, 0.f, 0.f, 0.f};

  STAGE_A(0, 0, 0); STAGE_B(0, 0, 0); STAGE_A(0, 1, 0); STAGE_B(0, 1, 0);
  STAGE_B(1, 0, 1); STAGE_A(1, 0, 1);
  VMC_STEADY();  // last 2 stages remain in flight; tile0 landed
  SB(); BAR(); SB();

  bf16x8 a[4][2], b[4][2];
  for (int T = 0; T < NT; ++T) {
    const int bs = T & 1;
    const char* Aw = ldsA + bs * BUF + wm * HALF + laneoff;
    const char* Bw = ldsB + bs * BUF + (wn >> 1) * HALF + (wn & 1) * 4096 + laneoff;
    // ---------- phase 0 ----------
#pragma unroll
    for (int mi = 0; mi < 4; ++mi)
#pragma unroll
      for (int kk = 0; kk < NKK; ++kk)
        a[mi][kk] = *(const bf16x8*)(Aw + mi * 1024 + kk * 8192);
#pragma unroll
    for (int ni = 0; ni < 2; ++ni)
#pragma unroll
      for (int kk = 0; kk < NKK; ++kk)
        b[ni][kk] = *(const bf16x8*)(Bw + ni * 1024 + kk * 8192);
    if (T + 1 < NT) STAGE_A(bs ^ 1, 1, T + 1);
    SB(); BAR(); SB();
    __builtin_amdgcn_s_setprio(1);
#pragma unroll
    for (int mi = 0; mi < 4; ++mi)
#pragma unroll
      for (int ni = 0; ni < 2; ++ni)
#pragma unroll
        for (int kk = 0; kk < NKK; ++kk)
          acc[mi][ni] = __builtin_amdgcn_mfma_f32_16x16x32_bf16(a[mi][kk], b[ni][kk], acc[mi][ni], 0, 0, 0);
    __builtin_amdgcn_s_setprio(0);
    SB(); BAR(); SB();
    // ---------- phase 1 ----------
#pragma unroll
    for (int ni = 2; ni < 4; ++ni)
#pragma unroll
      for (int kk = 0; kk < NKK; ++kk)
        b[ni][kk] = *(const bf16x8*)(Bw + ni * 1024 + kk * 8192);
    if (T + 1 < NT) STAGE_B(bs ^ 1, 1, T + 1);
    SB(); BAR(); SB();
    __builtin_amdgcn_s_setprio(1);
#pragma unroll
    for (int mi = 0; mi < 4; ++mi)
#pragma unroll
      for (int ni = 2; ni < 4; ++ni)
#pragma unroll
        for (int kk = 0; kk < NKK; ++kk)
          acc[mi][ni] = __builtin_amdgcn_mfma_f32_16x16x32_bf16(a[mi][kk], b[ni][kk], acc[mi][ni], 0, 0, 0);
    __builtin_amdgcn_s_setprio(0);
    SB(); BAR(); SB();
    // ---------- phase 2 ----------
#pragma unroll
    for (int mi = 0; mi < 4; ++mi)
#pragma unroll
      for (int kk = 0; kk < NKK; ++kk)
        a[mi][kk] = *(const bf16x8*)(Aw + (mi + 4) * 1024 + kk * 8192);
    if (T + 2 < NT) STAGE_B(bs, 0, T + 2);
    SB(); BAR(); SB();
    __builtin_amdgcn_s_setprio(1);
#pragma unroll
    for (int mi = 0; mi < 4; ++mi)
#pragma unroll
      for (int ni = 0; ni < 2; ++ni)
#pragma unroll
        for (int kk = 0; kk < NKK; ++kk)
          acc[mi + 4][ni] = __builtin_amdgcn_mfma_f32_16x16x32_bf16(a[mi][kk], b[ni][kk], acc[mi + 4][ni], 0, 0, 0);
    __builtin_amdgcn_s_setprio(0);
    SB(); BAR(); SB();
    // ---------- phase 3 ----------
    if (T + 2 < NT) STAGE_A(bs, 0, T + 2);
    if (T < NT - 2) { VMC_STEADY(); }
    else            { asm volatile("s_waitcnt vmcnt(0)" ::: "memory"); }
    SB(); BAR(); SB();
    __builtin_amdgcn_s_setprio(1);
#pragma unroll
    for (int mi = 0; mi < 4; ++mi)
#pragma unroll
      for (int ni = 2; ni < 4; ++ni)
#pragma unroll
        for (int kk = 0; kk < NKK; ++kk)
          acc[mi + 4][ni] = __builtin_amdgcn_mfma_f32_16x16x32_bf16(a[mi][kk], b[ni][kk], acc[mi + 4][ni], 0, 0, 0);
    __builtin_amdgcn_s_setprio(0);
    SB(); BAR(); SB();
  }
#undef STAGE_A
#undef STAGE_B
#undef SB
#undef BAR
#undef VMC_STEADY

  float bias_v[4];
#pragma unroll
  for (int ni = 0; ni < 4; ++ni)
    bias_v[ni] = bias[col0 + wn * 64 + ni * 16 + (lane & 15)];
  float* Cf = (float*)C;
  __hip_bfloat16* Cb = (__hip_bfloat16*)C;
#pragma unroll
  for (int mi = 0; mi < 8; ++mi) {
#pragma unroll
    for (int r2 = 0; r2 < 4; ++r2) {
      int m = row0 + wm * 128 + mi * 16 + (lane >> 4) * 4 + r2;
      if (m < Mreal) {
#pragma unroll
        for (int ni = 0; ni < 4; ++ni) {
          int n = col0 + wn * 64 + ni * 16 + (lane & 15);
          float v = acc[mi][ni][r2] + bias_v[ni];
          if (ACT == 1) v = gelu_exact(v);
          if (OUTBF) Cb[(size_t)m * N + n] = __float2bfloat16(v);
          else       Cf[(size_t)m * N + n] = v;
        }
      }
    }
  }
}

// ------------------------------------------------------------------
// Fused attention per (b,h): bf16 in/out, fp32 compute. S=100, hd=64.
// 256 threads: all stage K/V (2 iters), rows 0..99 compute.
// Sc padded to 101 (stride 100 = 8-way bank conflict; 101 coprime).
// ------------------------------------------------------------------
__global__ __launch_bounds__(256) void attn_kernel(const __hip_bfloat16* __restrict__ qkv,
                                                   __hip_bfloat16* __restrict__ ctx) {
  __shared__ float KV[50][64];
  __shared__ float Sc[100][101];
  int bh = blockIdx.x;  // b*H + h
  int b = bh >> 4, hh = bh & 15;
  int tid = threadIdx.x;
  size_t base = (size_t)b * S_ * (3 * D_);
  int hcol = hh * HD_;
  int r = tid;

  float qa[64];
  if (r < 100) {
    const __hip_bfloat16* qp = qkv + base + (size_t)r * (3 * D_) + hcol;
#pragma unroll
    for (int d0 = 0; d0 < 8; ++d0) {
      union { uint4 u; __hip_bfloat16 h[8]; } uu;
      uu.u = *(const uint4*)(qp + d0 * 8);
#pragma unroll
      for (int j = 0; j < 8; ++j) qa[d0 * 8 + j] = __bfloat162float(uu.h[j]);
    }
  }
  for (int tt = 0; tt < 2; ++tt) {
    __syncthreads();
    for (int idx = tid; idx < 400; idx += 256) {
      int j = idx >> 3, d8 = idx & 7;
      union { uint4 u; __hip_bfloat16 h[8]; } uu;
      uu.u = *(const uint4*)(qkv + base + (size_t)(tt * 50 + j) * (3 * D_) + D_ + hcol + d8 * 8);
#pragma unroll
      for (int e = 0; e < 8; ++e) KV[j][d8 * 8 + e] = __bfloat162float(uu.h[e]);
    }
    __syncthreads();
    if (r < 100) {
      for (int j = 0; j < 50; ++j) {
        float s = 0.f;
#pragma unroll
        for (int d0 = 0; d0 < 16; ++d0) {
          float4 kv = *(const float4*)&KV[j][d0 * 4];
          s += qa[d0 * 4 + 0] * kv.x + qa[d0 * 4 + 1] * kv.y +
               qa[d0 * 4 + 2] * kv.z + qa[d0 * 4 + 3] * kv.w;
        }
        Sc[r][tt * 50 + j] = s * 0.125f;
      }
    }
  }
  float inv_sum = 0.f;
  if (r < 100) {
    float mx = -1e30f;
    for (int j = 0; j < 100; ++j) mx = fmaxf(mx, Sc[r][j]);
    float sum = 0.f;
    for (int j = 0; j < 100; ++j) {
      float e = expf(Sc[r][j] - mx);
      Sc[r][j] = e;
      sum += e;
    }
    inv_sum = 1.0f / sum;
  }
  float ca[64];
#pragma unroll
  for (int d = 0; d < 64; ++d) ca[d] = 0.f;
  for (int tt = 0; tt < 2; ++tt) {
    __syncthreads();
    for (int idx = tid; idx < 400; idx += 256) {
      int j = idx >> 3, d8 = idx & 7;
      union { uint4 u; __hip_bfloat16 h[8]; } uu;
      uu.u = *(const uint4*)(qkv + base + (size_t)(tt * 50 + j) * (3 * D_) + 2 * D_ + hcol + d8 * 8);
#pragma unroll
      for (int e = 0; e < 8; ++e) KV[j][d8 * 8 + e] = __bfloat162float(uu.h[e]);
    }
    __syncthreads();
    if (r < 100) {
      for (int j = 0; j < 50; ++j) {
        float p = Sc[r][tt * 50 + j];
#pragma unroll
        for (int d0 = 0; d0 < 16; ++d0) {
          float4 kv = *(const float4*)&KV[j][d0 * 4];
          ca[d0 * 4 + 0] += p * kv.x;
          ca[d0 * 4 + 1] += p * kv.y;
          ca[d0 * 4 + 2] += p * kv.z;
          ca[d0 * 4 + 3] += p * kv.w;
        }
      }
    }
  }
  if (r < 100) {
    __hip_bfloat16* cp = ctx + ((size_t)b * S_ + r) * D_ + hcol;
#pragma unroll
    for (int d = 0; d < 64; ++d) cp[d] = __float2bfloat16(ca[d] * inv_sum);
  }
}

// ------------------------------------------------------------------
// h = LN(h + res [+ res2]) * scale + bias  (coalesced float4 per thread)
// ------------------------------------------------------------------
__device__ float block_sum_1024(float v) {
#pragma unroll
  for (int off = 32; off > 0; off >>= 1) v += __shfl_down(v, off);
  __shared__ float sm[4];
  __syncthreads();
  int lane = threadIdx.x & 63, wv = threadIdx.x >> 6;
  if (lane == 0) sm[wv] = v;
  __syncthreads();
  return sm[0] + sm[1] + sm[2] + sm[3];
}

__global__ __launch_bounds__(256) void add_ln_kernel(float* __restrict__ h,
    const float* __restrict__ res, const float* __restrict__ res2,
    const float* __restrict__ scale, const float* __restrict__ bias,
    __hip_bfloat16* __restrict__ hb) {
  size_t b4 = (size_t)blockIdx.x * 256 + threadIdx.x;  // float4 index within row-major stream
  float4 xa = ((const float4*)h)[b4];
  float4 xb = ((const float4*)res)[b4];
  float x[4] = {xa.x + xb.x, xa.y + xb.y, xa.z + xb.z, xa.w + xb.w};
  if (res2) {
    float4 xc = ((const float4*)res2)[b4];
    x[0] += xc.x; x[1] += xc.y; x[2] += xc.z; x[3] += xc.w;
  }
  float s = x[0] + x[1] + x[2] + x[3];
  float mu = block_sum_1024(s) * (1.0f / 1024.0f);
  float v = 0.f;
#pragma unroll
  for (int i = 0; i < 4; ++i) {
    float d = x[i] - mu;
    v += d * d;
  }
  float var = block_sum_1024(v) * (1.0f / 1024.0f);
  float rs = rsqrtf(var + 1e-5f);
  int d0 = threadIdx.x * 4;
  float4 sc = *(const float4*)&scale[d0];
  float4 bi = *(const float4*)&bias[d0];
  float o[4];
  o[0] = (x[0] - mu) * rs * sc.x + bi.x;
  o[1] = (x[1] - mu) * rs * sc.y + bi.y;
  o[2] = (x[2] - mu) * rs * sc.z + bi.z;
  o[3] = (x[3] - mu) * rs * sc.w + bi.w;
  ((float4*)h)[b4] = (float4){o[0], o[1], o[2], o[3]};
  union { __hip_bfloat16 hh[4]; uint2 u; } ob;
#pragma unroll
  for (int i = 0; i < 4; ++i) ob.hh[i] = __float2bfloat16(o[i]);
  ((uint2*)hb)[b4] = ob.u;
}

// ------------------------------------------------------------------
extern "C" void kernel_launch(void* const* d_in, const int* in_sizes, int n_in,
                              void* d_out, int out_size, void* d_ws, size_t ws_size,
                              hipStream_t stream) {
  const int* x       = (const int*)d_in[0];
  const float* emb   = (const float*)d_in[1];
  const float* pos   = (const float*)d_in[2];
  const float* qkv_w = (const float*)d_in[3];
  const float* qkv_b = (const float*)d_in[4];
  const float* out_w = (const float*)d_in[5];
  const float* out_b = (const float*)d_in[6];
  const float* ln1_s = (const float*)d_in[7];
  const float* ln1_b = (const float*)d_in[8];
  const float* ff1_w = (const float*)d_in[9];
  const float* ff1_b = (const float*)d_in[10];
  const float* ff2_w = (const float*)d_in[11];
  const float* ff2_b = (const float*)d_in[12];
  const float* ln2_s = (const float*)d_in[13];
  const float* ln2_b = (const float*)d_in[14];
  const float* dec_w = (const float*)d_in[15];
  const float* dec_b = (const float*)d_in[16];
  float* out = (float*)d_out;

  char* ws = (char*)d_ws;
  size_t off = 0;
  auto alloc = [&](size_t bytes) { void* p = ws + off; off += (bytes + 255) & ~(size_t)255; return p; };
  double* gpart           = (double*)alloc(NPART * 8);
  float* h                = (float*)alloc((size_t)3200 * 1024 * 4);
  __hip_bfloat16* h_bf    = (__hip_bfloat16*)alloc((size_t)MPAD * 1024 * 2);  // padded for 256-tiles
  float* tmp              = (float*)alloc((size_t)3200 * 1024 * 4);
  float* tmp2             = (float*)alloc((size_t)3200 * 1024 * 4);
  __hip_bfloat16* ctx_bf  = (__hip_bfloat16*)alloc((size_t)3200 * 1024 * 2);
  __hip_bfloat16* big_bf  = (__hip_bfloat16*)alloc((size_t)3200 * 4096 * 2);  // qkv out / ff1 out
  __hip_bfloat16* weff    = (__hip_bfloat16*)alloc((size_t)32000 * 1024 * 2);
  __hip_bfloat16* qkvw_bf = (__hip_bfloat16*)alloc((size_t)2 * 3072 * 1024 * 2);
  __hip_bfloat16* outw_bf = (__hip_bfloat16*)alloc((size_t)2 * 1024 * 1024 * 2);
  __hip_bfloat16* ff1w_bf = (__hip_bfloat16*)alloc((size_t)2 * 4096 * 1024 * 2);
  __hip_bfloat16* ff2w_bf = (__hip_bfloat16*)alloc((size_t)2 * 1024 * 4096 * 2);

  absmean_kernel<<<NPART, 256, 0, stream>>>(dec_w, gpart);
  quantize_kernel<<<4096, 256, 0, stream>>>(dec_w, gpart, weff);
  prep_kernel<<<3200 + 4096, 256, 0, stream>>>(x, emb, pos, h, h_bf,
                                               qkv_w, out_w, ff1_w, ff2_w,
                                               qkvw_bf, outw_bf, ff1w_bf, ff2w_bf);

  const int M = 3200;
  for (int l = 0; l < 2; ++l) {
    // qkv: 8-phase 256^2 BK=64 (156 blocks -> single cohort round)
    gemm256<0, 1, 64><<<dim3(MPAD / 256, 3072 / 256), 512, 131072, stream>>>(
        h_bf, qkvw_bf + (size_t)l * 3072 * 1024, qkv_b + l * 3072, big_bf,
        M, 3072, 1024);
    attn_kernel<<<512, 256, 0, stream>>>(big_bf, ctx_bf);
    // out-proj: split-K2 (z=0 -> tmp + bias, z=1 -> tmp2)
    gemm_bf<0, 0><<<dim3(M / 128, 1024 / 128, 2), 256, 0, stream>>>(
        ctx_bf, outw_bf + (size_t)l * 1024 * 1024, out_b + l * 1024, tmp, tmp2,
        M, 1024, 512, 1024, 1024);
    add_ln_kernel<<<M, 256, 0, stream>>>(h, tmp, tmp2, ln1_s + l * 1024, ln1_b + l * 1024, h_bf);
    // ff1: 8-phase 256^2 BK=64 (208 blocks -> single cohort round)
    gemm256<1, 1, 64><<<dim3(MPAD / 256, 4096 / 256), 512, 131072, stream>>>(
        h_bf, ff1w_bf + (size_t)l * 4096 * 1024, ff1_b + l * 4096, big_bf,
        M, 4096, 1024);
    // ff2: split-K2
    gemm_bf<0, 0><<<dim3(M / 128, 1024 / 128, 2), 256, 0, stream>>>(
        big_bf, ff2w_bf + (size_t)l * 1024 * 4096, ff2_b + l * 1024, tmp, tmp2,
        M, 1024, 2048, 4096, 4096);
    add_ln_kernel<<<M, 256, 0, stream>>>(h, tmp, tmp2, ln2_s + l * 1024, ln2_b + l * 1024, h_bf);
  }
  // ternary decoder: 8-phase 256^2 BK=32 (64KB LDS -> 2 blocks/CU so the
  // 1625-block grid gets cross-block overlap of barrier drains)
  gemm256<0, 0, 32><<<dim3(MPAD / 256, 32000 / 256), 512, 65536, stream>>>(
      h_bf, weff, dec_b, out, M, 32000, 1024);
}

// Round 12
// 880.659 us; speedup vs baseline: 2.8003x; 2.8003x over previous
//
#include <hip/hip_runtime.h>
#include <hip/hip_bf16.h>
#include <math.h>

#define B_ 32
#define S_ 100
#define D_ 1024
#define H_ 16
#define L_ 2
#define V_ 32000
#define DF_ 4096
#define HD_ 64
#define MPAD 3328   // 3200 padded to 13*256
#define NPART 2048  // absmean partial count

typedef __bf16 bf16x8 __attribute__((ext_vector_type(8)));
typedef float f32x4 __attribute__((ext_vector_type(4)));

__device__ __forceinline__ void async_copy16(const void* g, void* l) {
  __builtin_amdgcn_global_load_lds((const __attribute__((address_space(1))) void*)g,
                                   (__attribute__((address_space(3))) void*)l, 16, 0, 0);
}

// ------------------------------------------------------------------
// per-block |w| partial sums in f64 (no atomics, no memset; every
// entry rewritten each launch -> no cross-replay state)
// ------------------------------------------------------------------
__global__ __launch_bounds__(256) void absmean_kernel(const float* __restrict__ w,
                                                      double* __restrict__ part) {
  const long long n4 = (long long)V_ * D_ / 4;
  double s = 0.0;
  long long stride = (long long)gridDim.x * blockDim.x;
  for (long long i = (long long)blockIdx.x * blockDim.x + threadIdx.x; i < n4; i += stride) {
    float4 v = ((const float4*)w)[i];
    s += (double)fabsf(v.x) + (double)fabsf(v.y) + (double)fabsf(v.z) + (double)fabsf(v.w);
  }
#pragma unroll
  for (int off = 32; off > 0; off >>= 1) s += __shfl_down(s, off);
  __shared__ double sm[4];
  int lane = threadIdx.x & 63, wv = threadIdx.x >> 6;
  if (lane == 0) sm[wv] = s;
  __syncthreads();
  if (threadIdx.x == 0) part[blockIdx.x] = sm[0] + sm[1] + sm[2] + sm[3];
}

// packed effective ternary weight as bf16: {q==0:+1, q==+1:-1, q==-1:0}
// Each block first reduces the 2048 partials in a FIXED order (bitwise
// deterministic, identical across blocks), then quantizes with w*inv_g
// (<=1ulp vs w/g, below the ~1e-13 reduction-order band already accepted).
__global__ __launch_bounds__(256) void quantize_kernel(const float* __restrict__ w,
    const double* __restrict__ part, __hip_bfloat16* __restrict__ q) {
  __shared__ double gsh;
  {
    double p = 0.0;
    for (int i = threadIdx.x; i < NPART; i += 256) p += part[i];
#pragma unroll
    for (int off = 32; off > 0; off >>= 1) p += __shfl_down(p, off);
    __shared__ double sm[4];
    int lane = threadIdx.x & 63, wv = threadIdx.x >> 6;
    if (lane == 0) sm[wv] = p;
    __syncthreads();
    if (threadIdx.x == 0) gsh = sm[0] + sm[1] + sm[2] + sm[3];
    __syncthreads();
  }
  double g = gsh / ((double)V_ * D_) + 1e-6;
  double inv_g = 1.0 / g;
  const long long n4 = (long long)V_ * D_ / 4;
  long long stride = (long long)gridDim.x * blockDim.x;
  for (long long i = (long long)blockIdx.x * blockDim.x + threadIdx.x; i < n4; i += stride) {
    float4 v = ((const float4*)w)[i];
    union { __hip_bfloat16 h[4]; uint2 u; } o;
    float vv[4] = {v.x, v.y, v.z, v.w};
#pragma unroll
    for (int j = 0; j < 4; ++j) {
      double r = rint((double)vv[j] * inv_g);  // half-to-even, matches np.round
      r = fmin(1.0, fmax(-1.0, r));
      float w_eff = (r == 0.0) ? 1.0f : ((r == 1.0) ? -1.0f : 0.0f);
      o.h[j] = __float2bfloat16(w_eff);  // exact
    }
    ((uint2*)q)[i] = o.u;
  }
}

// ------------------------------------------------------------------
// fused: blocks [0,3200) embed one row each (h fp32 + h_bf bf16);
// blocks [3200, 3200+4096) grid-stride cast the four weight tensors.
// ------------------------------------------------------------------
__global__ __launch_bounds__(256) void prep_kernel(const int* __restrict__ x,
    const float* __restrict__ emb, const float* __restrict__ pos,
    float* __restrict__ h, __hip_bfloat16* __restrict__ hb,
    const float* __restrict__ qkv_w, const float* __restrict__ out_w,
    const float* __restrict__ ff1_w, const float* __restrict__ ff2_w,
    __hip_bfloat16* __restrict__ qd, __hip_bfloat16* __restrict__ od,
    __hip_bfloat16* __restrict__ f1d, __hip_bfloat16* __restrict__ f2d) {
  if (blockIdx.x < 3200) {
    int row = blockIdx.x;  // b*S + s
    int s = row % S_;
    int tok = x[row];
    size_t eb = (size_t)tok * D_, pb = (size_t)s * D_, hb0 = (size_t)row * D_;
#pragma unroll
    for (int i = 0; i < 4; ++i) {
      int d = threadIdx.x + i * 256;
      float v = emb[eb + d] + pos[pb + d];
      h[hb0 + d] = v;
      hb[hb0 + d] = __float2bfloat16(v);
    }
    return;
  }
  const long long n1 = (long long)2 * 3072 * 1024 / 4;
  const long long n2 = n1 + (long long)2 * 1024 * 1024 / 4;
  const long long n3 = n2 + (long long)2 * 4096 * 1024 / 4;
  const long long n4 = n3 + (long long)2 * 1024 * 4096 / 4;
  long long cb = (long long)(blockIdx.x - 3200);
  long long stride = (long long)(gridDim.x - 3200) * blockDim.x;
  for (long long i = cb * blockDim.x + threadIdx.x; i < n4; i += stride) {
    const float* src; __hip_bfloat16* dst; long long j;
    if (i < n1)      { src = qkv_w; dst = qd;  j = i; }
    else if (i < n2) { src = out_w; dst = od;  j = i - n1; }
    else if (i < n3) { src = ff1_w; dst = f1d; j = i - n2; }
    else             { src = ff2_w; dst = f2d; j = i - n3; }
    float4 v = ((const float4*)src)[j];
    union { __hip_bfloat16 h[4]; uint2 u; } o;
    o.h[0] = __float2bfloat16(v.x);
    o.h[1] = __float2bfloat16(v.y);
    o.h[2] = __float2bfloat16(v.z);
    o.h[3] = __float2bfloat16(v.w);
    ((uint2*)dst)[j] = o.u;
  }
}

__device__ __forceinline__ float gelu_exact(float v) {
  return 0.5f * v * (1.0f + erff(v * 0.70710678118654752f));
}

// ------------------------------------------------------------------
// m97-structure bf16 MFMA GEMM, 128x128 tile, BK=64 single-buffered
// (R6-proven; explicit dbuf regressed by cutting occupancy). Split-K
// via blockIdx.z (z=0 -> C+bias, z=1 -> C2). XCD-bijective swizzle.
// ------------------------------------------------------------------
template <int ACT, int OUTBF>
__global__ __launch_bounds__(256) void gemm_bf(const __hip_bfloat16* __restrict__ A,
    const __hip_bfloat16* __restrict__ Bm, const float* __restrict__ bias,
    void* __restrict__ C, void* __restrict__ C2, int M, int N, int K, int lda, int ldb) {
  __shared__ __bf16 As[128 * 64];  // [0..8191B] k0-31, [8192..16383B] k32-63
  __shared__ __bf16 Bs[128 * 64];
  int tid = threadIdx.x;
  int lane = tid & 63, wid = tid >> 6;
  int wr = wid >> 1, wc = wid & 1;  // wave -> 64x64 quadrant
  int z = blockIdx.z;

  // ---- bijective XCD swizzle (T1 / m204) ----
  int nwg = gridDim.x * gridDim.y;
  int orig = blockIdx.y * gridDim.x + blockIdx.x;
  int q = nwg >> 3, r = nwg & 7;
  int xcd = orig & 7, local = orig >> 3;
  int wgid = (xcd < r ? xcd * (q + 1) : r * (q + 1) + (xcd - r) * q) + local;
  int row0 = (wgid % gridDim.x) * 128;  // gridDim.x = M/128 (M fastest)
  int col0 = (wgid / gridDim.x) * 128;

  const __hip_bfloat16* Az = A + (size_t)z * K;
  const __hip_bfloat16* Bz = Bm + (size_t)z * K;
  int j0 = wid * 2;
  const __hip_bfloat16* Ag0 = Az + (size_t)(row0 + j0 * 16 + (lane >> 2)) * lda + (lane & 3) * 8;
  const __hip_bfloat16* Ag1 = Az + (size_t)(row0 + (j0 + 1) * 16 + (lane >> 2)) * lda + (lane & 3) * 8;
  const __hip_bfloat16* Bg0 = Bz + (size_t)(col0 + j0 * 16 + (lane >> 2)) * ldb + (lane & 3) * 8;
  const __hip_bfloat16* Bg1 = Bz + (size_t)(col0 + (j0 + 1) * 16 + (lane >> 2)) * ldb + (lane & 3) * 8;
  __bf16* Al0 = As + j0 * 512;
  __bf16* Al1 = As + (j0 + 1) * 512;
  __bf16* Bl0 = Bs + j0 * 512;
  __bf16* Bl1 = Bs + (j0 + 1) * 512;

  float bias_v[4];
#pragma unroll
  for (int ni = 0; ni < 4; ++ni)
    bias_v[ni] = (z == 0) ? bias[col0 + wc * 64 + ni * 16 + (lane & 15)] : 0.f;

  f32x4 acc[4][4];
#pragma unroll
  for (int mi = 0; mi < 4; ++mi)
#pragma unroll
    for (int ni = 0; ni < 4; ++ni) acc[mi][ni] = (f32x4){0.f, 0.f, 0.f, 0.f};

  const bf16x8* Asv = reinterpret_cast<const bf16x8*>(As);
  const bf16x8* Bsv = reinterpret_cast<const bf16x8*>(Bs);
  int afr = (wr * 64 + (lane & 15)) * 4 + (lane >> 4);  // in 8-elem units
  int bfr = (wc * 64 + (lane & 15)) * 4 + (lane >> 4);

  for (int k0 = 0; k0 < K; k0 += 64) {
    async_copy16(Ag0, Al0);  async_copy16(Ag0 + 32, (char*)Al0 + 8192);
    async_copy16(Ag1, Al1);  async_copy16(Ag1 + 32, (char*)Al1 + 8192);
    async_copy16(Bg0, Bl0);  async_copy16(Bg0 + 32, (char*)Bl0 + 8192);
    async_copy16(Bg1, Bl1);  async_copy16(Bg1 + 32, (char*)Bl1 + 8192);
    Ag0 += 64; Ag1 += 64; Bg0 += 64; Bg1 += 64;
    __syncthreads();  // drains vmcnt: LDS tile visible to all waves
    bf16x8 af[4][2], bq[4][2];
#pragma unroll
    for (int mi = 0; mi < 4; ++mi)
#pragma unroll
      for (int kk = 0; kk < 2; ++kk) af[mi][kk] = Asv[afr + mi * 64 + kk * 512];
#pragma unroll
    for (int ni = 0; ni < 4; ++ni)
#pragma unroll
      for (int kk = 0; kk < 2; ++kk) bq[ni][kk] = Bsv[bfr + ni * 64 + kk * 512];
#pragma unroll
    for (int mi = 0; mi < 4; ++mi)
#pragma unroll
      for (int ni = 0; ni < 4; ++ni)
#pragma unroll
        for (int kk = 0; kk < 2; ++kk)
          acc[mi][ni] = __builtin_amdgcn_mfma_f32_16x16x32_bf16(af[mi][kk], bq[ni][kk], acc[mi][ni], 0, 0, 0);
    __syncthreads();  // compute done before next-tile overwrite
  }

  float* Cf = (float*)((z == 0) ? C : C2);
  __hip_bfloat16* Cb = (__hip_bfloat16*)C;
#pragma unroll
  for (int mi = 0; mi < 4; ++mi) {
#pragma unroll
    for (int r2 = 0; r2 < 4; ++r2) {
      size_t m = row0 + wr * 64 + mi * 16 + (lane >> 4) * 4 + r2;
#pragma unroll
      for (int ni = 0; ni < 4; ++ni) {
        size_t n = col0 + wc * 64 + ni * 16 + (lane & 15);
        float v = acc[mi][ni][r2] + bias_v[ni];
        if (ACT == 1) v = gelu_exact(v);
        if (OUTBF) Cb[m * N + n] = __float2bfloat16(v);
        else       Cf[m * N + n] = v;
      }
    }
  }
}

// ------------------------------------------------------------------
// 8-phase 256x256 GEMM (T2+T3+T4+T5), BK=64, 512 threads = 8 waves
// (2M x 4N), per-wave 128x64 output. LDS 128 KiB, 1 block/CU. Raw
// s_barrier + counted vmcnt(4); XOR swizzle via pre-swizzled global
// source. NOTE: 2-blocks/CU variants are infeasible — the 256^2 tile's
// acc[8][4] f32x4 = 128 VGPR/wave cannot fit the <=128 VGPR budget that
// 16 waves/CU requires (R11: forced bound -> acc spilled to scratch,
// 12 GB phantom traffic, 6.7x slower). Keep launch_bounds(512,1).
// ------------------------------------------------------------------
template <int ACT, int OUTBF>
__global__ __launch_bounds__(512, 1) void gemm256(
    const __hip_bfloat16* __restrict__ A, const __hip_bfloat16* __restrict__ Bm,
    const float* __restrict__ bias, void* __restrict__ C,
    int Mreal, int N, int K) {
  extern __shared__ char lds[];
  char* ldsA = lds;            // 65536 B
  char* ldsB = lds + 65536;    // 65536 B
  const int t = threadIdx.x;
  const int lane = t & 63, wid = t >> 6;
  const int wm = wid >> 2, wn = wid & 3;
  const int NT = K >> 6;

  // bijective XCD swizzle, M fastest
  int nwg = gridDim.x * gridDim.y;
  int orig = blockIdx.y * gridDim.x + blockIdx.x;
  int q = nwg >> 3, r = nwg & 7;
  int xcd = orig & 7, local = orig >> 3;
  int wgid = (xcd < r ? xcd * (q + 1) : r * (q + 1) + (xcd - r) * q) + local;
  int row0 = (wgid % gridDim.x) * 256;
  int col0 = (wgid / gridDim.x) * 256;

  const int rs = t >> 2;                                           // 0..127
  const int kc = ((((t & 3) << 4) ^ (((t >> 5) & 1) << 5)) >> 1);  // 0..31
  const __hip_bfloat16* Asrc = A + (size_t)(row0 + rs) * K + kc;
  const __hip_bfloat16* Bsrc = Bm + (size_t)(col0 + rs) * K + kc;

#define STAGE_A(b, h, tgt) do { \
    const __hip_bfloat16* _s = Asrc + (size_t)(h) * 128 * K + (tgt) * 64; \
    char* _d = ldsA + (b) * 32768 + (h) * 16384 + t * 16; \
    async_copy16(_s, _d); async_copy16(_s + 32, _d + 8192); } while (0)
#define STAGE_B(b, h, tgt) do { \
    const __hip_bfloat16* _s = Bsrc + (size_t)(h) * 128 * K + (tgt) * 64; \
    char* _d = ldsB + (b) * 32768 + (h) * 16384 + t * 16; \
    async_copy16(_s, _d); async_copy16(_s + 32, _d + 8192); } while (0)
#define SB() __builtin_amdgcn_sched_barrier(0)
#define BAR() __builtin_amdgcn_s_barrier()

  const int sb5 = ((lane >> 3) & 1) << 5;
  const int laneoff = ((lane & 15) << 6) + (((lane >> 4) << 4) ^ sb5);

  f32x4 acc[8][4];
#pragma unroll
  for (int i = 0; i < 8; ++i)
#pragma unroll
    for (int j = 0; j < 4; ++j) acc[i][j] = (f32x4){0.f, 0.f, 0.f, 0.f};

  STAGE_A(0, 0, 0); STAGE_B(0, 0, 0); STAGE_A(0, 1, 0); STAGE_B(0, 1, 0);
  STAGE_B(1, 0, 1); STAGE_A(1, 0, 1);
  asm volatile("s_waitcnt vmcnt(4)" ::: "memory");
  SB(); BAR(); SB();

  bf16x8 a[4][2], b[4][2];
  for (int T = 0; T < NT; ++T) {
    const int bs = T & 1;
    const char* Aw = ldsA + bs * 32768 + wm * 16384 + laneoff;
    const char* Bw = ldsB + bs * 32768 + (wn >> 1) * 16384 + (wn & 1) * 4096 + laneoff;
    // ---------- phase 0 ----------
#pragma unroll
    for (int mi = 0; mi < 4; ++mi)
#pragma unroll
      for (int kk = 0; kk < 2; ++kk)
        a[mi][kk] = *(const bf16x8*)(Aw + mi * 1024 + kk * 8192);
#pragma unroll
    for (int ni = 0; ni < 2; ++ni)
#pragma unroll
      for (int kk = 0; kk < 2; ++kk)
        b[ni][kk] = *(const bf16x8*)(Bw + ni * 1024 + kk * 8192);
    if (T + 1 < NT) STAGE_A(bs ^ 1, 1, T + 1);
    SB(); BAR(); SB();
    __builtin_amdgcn_s_setprio(1);
#pragma unroll
    for (int mi = 0; mi < 4; ++mi)
#pragma unroll
      for (int ni = 0; ni < 2; ++ni)
#pragma unroll
        for (int kk = 0; kk < 2; ++kk)
          acc[mi][ni] = __builtin_amdgcn_mfma_f32_16x16x32_bf16(a[mi][kk], b[ni][kk], acc[mi][ni], 0, 0, 0);
    __builtin_amdgcn_s_setprio(0);
    SB(); BAR(); SB();
    // ---------- phase 1 ----------
#pragma unroll
    for (int ni = 2; ni < 4; ++ni)
#pragma unroll
      for (int kk = 0; kk < 2; ++kk)
        b[ni][kk] = *(const bf16x8*)(Bw + ni * 1024 + kk * 8192);
    if (T + 1 < NT) STAGE_B(bs ^ 1, 1, T + 1);
    SB(); BAR(); SB();
    __builtin_amdgcn_s_setprio(1);
#pragma unroll
    for (int mi = 0; mi < 4; ++mi)
#pragma unroll
      for (int ni = 2; ni < 4; ++ni)
#pragma unroll
        for (int kk = 0; kk < 2; ++kk)
          acc[mi][ni] = __builtin_amdgcn_mfma_f32_16x16x32_bf16(a[mi][kk], b[ni][kk], acc[mi][ni], 0, 0, 0);
    __builtin_amdgcn_s_setprio(0);
    SB(); BAR(); SB();
    // ---------- phase 2 ----------
#pragma unroll
    for (int mi = 0; mi < 4; ++mi)
#pragma unroll
      for (int kk = 0; kk < 2; ++kk)
        a[mi][kk] = *(const bf16x8*)(Aw + (mi + 4) * 1024 + kk * 8192);
    if (T + 2 < NT) STAGE_B(bs, 0, T + 2);
    SB(); BAR(); SB();
    __builtin_amdgcn_s_setprio(1);
#pragma unroll
    for (int mi = 0; mi < 4; ++mi)
#pragma unroll
      for (int ni = 0; ni < 2; ++ni)
#pragma unroll
        for (int kk = 0; kk < 2; ++kk)
          acc[mi + 4][ni] = __builtin_amdgcn_mfma_f32_16x16x32_bf16(a[mi][kk], b[ni][kk], acc[mi + 4][ni], 0, 0, 0);
    __builtin_amdgcn_s_setprio(0);
    SB(); BAR(); SB();
    // ---------- phase 3 ----------
    if (T + 2 < NT) STAGE_A(bs, 0, T + 2);
    if (T < NT - 2) { asm volatile("s_waitcnt vmcnt(4)" ::: "memory"); }
    else            { asm volatile("s_waitcnt vmcnt(0)" ::: "memory"); }
    SB(); BAR(); SB();
    __builtin_amdgcn_s_setprio(1);
#pragma unroll
    for (int mi = 0; mi < 4; ++mi)
#pragma unroll
      for (int ni = 2; ni < 4; ++ni)
#pragma unroll
        for (int kk = 0; kk < 2; ++kk)
          acc[mi + 4][ni] = __builtin_amdgcn_mfma_f32_16x16x32_bf16(a[mi][kk], b[ni][kk], acc[mi + 4][ni], 0, 0, 0);
    __builtin_amdgcn_s_setprio(0);
    SB(); BAR(); SB();
  }
#undef STAGE_A
#undef STAGE_B
#undef SB
#undef BAR

  float bias_v[4];
#pragma unroll
  for (int ni = 0; ni < 4; ++ni)
    bias_v[ni] = bias[col0 + wn * 64 + ni * 16 + (lane & 15)];
  float* Cf = (float*)C;
  __hip_bfloat16* Cb = (__hip_bfloat16*)C;
#pragma unroll
  for (int mi = 0; mi < 8; ++mi) {
#pragma unroll
    for (int r2 = 0; r2 < 4; ++r2) {
      int m = row0 + wm * 128 + mi * 16 + (lane >> 4) * 4 + r2;
      if (m < Mreal) {
#pragma unroll
        for (int ni = 0; ni < 4; ++ni) {
          int n = col0 + wn * 64 + ni * 16 + (lane & 15);
          float v = acc[mi][ni][r2] + bias_v[ni];
          if (ACT == 1) v = gelu_exact(v);
          if (OUTBF) Cb[(size_t)m * N + n] = __float2bfloat16(v);
          else       Cf[(size_t)m * N + n] = v;
        }
      }
    }
  }
}

// ------------------------------------------------------------------
// Fused attention per (b,h): bf16 in/out, fp32 compute. S=100, hd=64.
// 256 threads: all stage K/V (2 iters), rows 0..99 compute.
// Sc padded to 101 (stride 100 = 8-way bank conflict; 101 coprime).
// ------------------------------------------------------------------
__global__ __launch_bounds__(256) void attn_kernel(const __hip_bfloat16* __restrict__ qkv,
                                                   __hip_bfloat16* __restrict__ ctx) {
  __shared__ float KV[50][64];
  __shared__ float Sc[100][101];
  int bh = blockIdx.x;  // b*H + h
  int b = bh >> 4, hh = bh & 15;
  int tid = threadIdx.x;
  size_t base = (size_t)b * S_ * (3 * D_);
  int hcol = hh * HD_;
  int r = tid;

  float qa[64];
  if (r < 100) {
    const __hip_bfloat16* qp = qkv + base + (size_t)r * (3 * D_) + hcol;
#pragma unroll
    for (int d0 = 0; d0 < 8; ++d0) {
      union { uint4 u; __hip_bfloat16 h[8]; } uu;
      uu.u = *(const uint4*)(qp + d0 * 8);
#pragma unroll
      for (int j = 0; j < 8; ++j) qa[d0 * 8 + j] = __bfloat162float(uu.h[j]);
    }
  }
  for (int tt = 0; tt < 2; ++tt) {
    __syncthreads();
    for (int idx = tid; idx < 400; idx += 256) {
      int j = idx >> 3, d8 = idx & 7;
      union { uint4 u; __hip_bfloat16 h[8]; } uu;
      uu.u = *(const uint4*)(qkv + base + (size_t)(tt * 50 + j) * (3 * D_) + D_ + hcol + d8 * 8);
#pragma unroll
      for (int e = 0; e < 8; ++e) KV[j][d8 * 8 + e] = __bfloat162float(uu.h[e]);
    }
    __syncthreads();
    if (r < 100) {
      for (int j = 0; j < 50; ++j) {
        float s = 0.f;
#pragma unroll
        for (int d0 = 0; d0 < 16; ++d0) {
          float4 kv = *(const float4*)&KV[j][d0 * 4];
          s += qa[d0 * 4 + 0] * kv.x + qa[d0 * 4 + 1] * kv.y +
               qa[d0 * 4 + 2] * kv.z + qa[d0 * 4 + 3] * kv.w;
        }
        Sc[r][tt * 50 + j] = s * 0.125f;
      }
    }
  }
  float inv_sum = 0.f;
  if (r < 100) {
    float mx = -1e30f;
    for (int j = 0; j < 100; ++j) mx = fmaxf(mx, Sc[r][j]);
    float sum = 0.f;
    for (int j = 0; j < 100; ++j) {
      float e = expf(Sc[r][j] - mx);
      Sc[r][j] = e;
      sum += e;
    }
    inv_sum = 1.0f / sum;
  }
  float ca[64];
#pragma unroll
  for (int d = 0; d < 64; ++d) ca[d] = 0.f;
  for (int tt = 0; tt < 2; ++tt) {
    __syncthreads();
    for (int idx = tid; idx < 400; idx += 256) {
      int j = idx >> 3, d8 = idx & 7;
      union { uint4 u; __hip_bfloat16 h[8]; } uu;
      uu.u = *(const uint4*)(qkv + base + (size_t)(tt * 50 + j) * (3 * D_) + 2 * D_ + hcol + d8 * 8);
#pragma unroll
      for (int e = 0; e < 8; ++e) KV[j][d8 * 8 + e] = __bfloat162float(uu.h[e]);
    }
    __syncthreads();
    if (r < 100) {
      for (int j = 0; j < 50; ++j) {
        float p = Sc[r][tt * 50 + j];
#pragma unroll
        for (int d0 = 0; d0 < 16; ++d0) {
          float4 kv = *(const float4*)&KV[j][d0 * 4];
          ca[d0 * 4 + 0] += p * kv.x;
          ca[d0 * 4 + 1] += p * kv.y;
          ca[d0 * 4 + 2] += p * kv.z;
          ca[d0 * 4 + 3] += p * kv.w;
        }
      }
    }
  }
  if (r < 100) {
    __hip_bfloat16* cp = ctx + ((size_t)b * S_ + r) * D_ + hcol;
#pragma unroll
    for (int d = 0; d < 64; ++d) cp[d] = __float2bfloat16(ca[d] * inv_sum);
  }
}

// ------------------------------------------------------------------
// h = LN(h + res [+ res2]) * scale + bias  (coalesced float4 per thread)
// ------------------------------------------------------------------
__device__ float block_sum_1024(float v) {
#pragma unroll
  for (int off = 32; off > 0; off >>= 1) v += __shfl_down(v, off);
  __shared__ float sm[4];
  __syncthreads();
  int lane = threadIdx.x & 63, wv = threadIdx.x >> 6;
  if (lane == 0) sm[wv] = v;
  __syncthreads();
  return sm[0] + sm[1] + sm[2] + sm[3];
}

__global__ __launch_bounds__(256) void add_ln_kernel(float* __restrict__ h,
    const float* __restrict__ res, const float* __restrict__ res2,
    const float* __restrict__ scale, const float* __restrict__ bias,
    __hip_bfloat16* __restrict__ hb) {
  size_t b4 = (size_t)blockIdx.x * 256 + threadIdx.x;  // float4 index within row-major stream
  float4 xa = ((const float4*)h)[b4];
  float4 xb = ((const float4*)res)[b4];
  float x[4] = {xa.x + xb.x, xa.y + xb.y, xa.z + xb.z, xa.w + xb.w};
  if (res2) {
    float4 xc = ((const float4*)res2)[b4];
    x[0] += xc.x; x[1] += xc.y; x[2] += xc.z; x[3] += xc.w;
  }
  float s = x[0] + x[1] + x[2] + x[3];
  float mu = block_sum_1024(s) * (1.0f / 1024.0f);
  float v = 0.f;
#pragma unroll
  for (int i = 0; i < 4; ++i) {
    float d = x[i] - mu;
    v += d * d;
  }
  float var = block_sum_1024(v) * (1.0f / 1024.0f);
  float rs = rsqrtf(var + 1e-5f);
  int d0 = threadIdx.x * 4;
  float4 sc = *(const float4*)&scale[d0];
  float4 bi = *(const float4*)&bias[d0];
  float o[4];
  o[0] = (x[0] - mu) * rs * sc.x + bi.x;
  o[1] = (x[1] - mu) * rs * sc.y + bi.y;
  o[2] = (x[2] - mu) * rs * sc.z + bi.z;
  o[3] = (x[3] - mu) * rs * sc.w + bi.w;
  ((float4*)h)[b4] = (float4){o[0], o[1], o[2], o[3]};
  union { __hip_bfloat16 hh[4]; uint2 u; } ob;
#pragma unroll
  for (int i = 0; i < 4; ++i) ob.hh[i] = __float2bfloat16(o[i]);
  ((uint2*)hb)[b4] = ob.u;
}

// ------------------------------------------------------------------
extern "C" void kernel_launch(void* const* d_in, const int* in_sizes, int n_in,
                              void* d_out, int out_size, void* d_ws, size_t ws_size,
                              hipStream_t stream) {
  const int* x       = (const int*)d_in[0];
  const float* emb   = (const float*)d_in[1];
  const float* pos   = (const float*)d_in[2];
  const float* qkv_w = (const float*)d_in[3];
  const float* qkv_b = (const float*)d_in[4];
  const float* out_w = (const float*)d_in[5];
  const float* out_b = (const float*)d_in[6];
  const float* ln1_s = (const float*)d_in[7];
  const float* ln1_b = (const float*)d_in[8];
  const float* ff1_w = (const float*)d_in[9];
  const float* ff1_b = (const float*)d_in[10];
  const float* ff2_w = (const float*)d_in[11];
  const float* ff2_b = (const float*)d_in[12];
  const float* ln2_s = (const float*)d_in[13];
  const float* ln2_b = (const float*)d_in[14];
  const float* dec_w = (const float*)d_in[15];
  const float* dec_b = (const float*)d_in[16];
  float* out = (float*)d_out;

  char* ws = (char*)d_ws;
  size_t off = 0;
  auto alloc = [&](size_t bytes) { void* p = ws + off; off += (bytes + 255) & ~(size_t)255; return p; };
  double* gpart           = (double*)alloc(NPART * 8);
  float* h                = (float*)alloc((size_t)3200 * 1024 * 4);
  __hip_bfloat16* h_bf    = (__hip_bfloat16*)alloc((size_t)MPAD * 1024 * 2);  // padded for 256-tiles
  float* tmp              = (float*)alloc((size_t)3200 * 1024 * 4);
  float* tmp2             = (float*)alloc((size_t)3200 * 1024 * 4);
  __hip_bfloat16* ctx_bf  = (__hip_bfloat16*)alloc((size_t)3200 * 1024 * 2);
  __hip_bfloat16* big_bf  = (__hip_bfloat16*)alloc((size_t)3200 * 4096 * 2);  // qkv out / ff1 out
  __hip_bfloat16* weff    = (__hip_bfloat16*)alloc((size_t)32000 * 1024 * 2);
  __hip_bfloat16* qkvw_bf = (__hip_bfloat16*)alloc((size_t)2 * 3072 * 1024 * 2);
  __hip_bfloat16* outw_bf = (__hip_bfloat16*)alloc((size_t)2 * 1024 * 1024 * 2);
  __hip_bfloat16* ff1w_bf = (__hip_bfloat16*)alloc((size_t)2 * 4096 * 1024 * 2);
  __hip_bfloat16* ff2w_bf = (__hip_bfloat16*)alloc((size_t)2 * 1024 * 4096 * 2);

  absmean_kernel<<<NPART, 256, 0, stream>>>(dec_w, gpart);
  quantize_kernel<<<4096, 256, 0, stream>>>(dec_w, gpart, weff);
  prep_kernel<<<3200 + 4096, 256, 0, stream>>>(x, emb, pos, h, h_bf,
                                               qkv_w, out_w, ff1_w, ff2_w,
                                               qkvw_bf, outw_bf, ff1w_bf, ff2w_bf);

  const int M = 3200;
  for (int l = 0; l < 2; ++l) {
    // qkv: 8-phase 256^2 (156 blocks -> single cohort round)
    gemm256<0, 1><<<dim3(MPAD / 256, 3072 / 256), 512, 131072, stream>>>(
        h_bf, qkvw_bf + (size_t)l * 3072 * 1024, qkv_b + l * 3072, big_bf,
        M, 3072, 1024);
    attn_kernel<<<512, 256, 0, stream>>>(big_bf, ctx_bf);
    // out-proj: split-K2 (z=0 -> tmp + bias, z=1 -> tmp2)
    gemm_bf<0, 0><<<dim3(M / 128, 1024 / 128, 2), 256, 0, stream>>>(
        ctx_bf, outw_bf + (size_t)l * 1024 * 1024, out_b + l * 1024, tmp, tmp2,
        M, 1024, 512, 1024, 1024);
    add_ln_kernel<<<M, 256, 0, stream>>>(h, tmp, tmp2, ln1_s + l * 1024, ln1_b + l * 1024, h_bf);
    // ff1: 8-phase 256^2 (208 blocks -> single cohort round)
    gemm256<1, 1><<<dim3(MPAD / 256, 4096 / 256), 512, 131072, stream>>>(
        h_bf, ff1w_bf + (size_t)l * 4096 * 1024, ff1_b + l * 4096, big_bf,
        M, 4096, 1024);
    // ff2: split-K2
    gemm_bf<0, 0><<<dim3(M / 128, 1024 / 128, 2), 256, 0, stream>>>(
        big_bf, ff2w_bf + (size_t)l * 1024 * 4096, ff2_b + l * 1024, tmp, tmp2,
        M, 1024, 2048, 4096, 4096);
    add_ln_kernel<<<M, 256, 0, stream>>>(h, tmp, tmp2, ln2_s + l * 1024, ln2_b + l * 1024, h_bf);
  }
  // ternary decoder: out = h @ w_eff^T + dec_b  (8-phase 256^2, padded M,
  // BK=64 / 128KB LDS / 1 block-CU — proven 278 us; see gemm256 header note)
  gemm256<0, 0><<<dim3(MPAD / 256, 32000 / 256), 512, 131072, stream>>>(
      h_bf, weff, dec_b, out, M, 32000, 1024);
}